// Round 5
// baseline (318.266 us; speedup 1.0000x reference)
//
#include <hip/hip_runtime.h>
#include <hip/hip_bf16.h>
#include <math.h>

// Problem constants (B,C,L,H fixed by setup_inputs)
#define NB 8
#define NC 512
#define NL 8192
#define NH 128
#define FEPS 1e-5f
#define NKEEP 358   // int(512*0.7)

typedef __attribute__((ext_vector_type(8))) short short8;
typedef __attribute__((ext_vector_type(4))) float f32x4;

__device__ __forceinline__ unsigned short f2bf(float x) {
  unsigned u = __float_as_uint(x);
  return (unsigned short)((u + 0x7fffu + ((u >> 16) & 1u)) >> 16);  // RNE
}
__device__ __forceinline__ unsigned pack2(float a, float b) {
  return (unsigned)f2bf(a) | ((unsigned)f2bf(b) << 16);
}

// ---------------- K1: per-(b,c) sum/sumsq of x over L; blocks 0..255 also prep weights ----------------
// Near-roofline streamer (~5.4 TB/s): contiguous float4, no barriers in the stream.
__global__ __launch_bounds__(256) void k1_xstats(
    const float* __restrict__ x, float* __restrict__ xsum, float* __restrict__ xsumsq,
    const float* __restrict__ gw1, const float* __restrict__ gw2,
    unsigned short* __restrict__ gw1b, unsigned short* __restrict__ gw2b,
    float* __restrict__ csum, float* __restrict__ gsum) {
  const int bc = blockIdx.x;
  const int t = threadIdx.x;
  if (bc < 256) {                       // fused weight prep (65536 = H*C = C*H elems)
    const int i = bc * 256 + t;
    gw1b[i] = f2bf(gw1[i]);
    gw2b[i] = f2bf(gw2[i]);
    if (i < NB * NC) { csum[i] = 0.f; gsum[i] = 0.f; }
  }
  const float4* xp = reinterpret_cast<const float4*>(x + (size_t)bc * NL);
  float s1 = 0.f, s2 = 0.f;
#pragma unroll
  for (int i = 0; i < 8; ++i) {
    float4 v = xp[i * 256 + t];
    s1 += v.x + v.y + v.z + v.w;
    s2 += v.x * v.x + v.y * v.y + v.z * v.z + v.w * v.w;
  }
  for (int off = 32; off; off >>= 1) { s1 += __shfl_down(s1, off); s2 += __shfl_down(s2, off); }
  __shared__ float r1[4], r2[4];
  if ((t & 63) == 0) { r1[t >> 6] = s1; r2[t >> 6] = s2; }
  __syncthreads();
  if (t == 0) {
    xsum[bc]   = r1[0] + r1[1] + r1[2] + r1[3];
    xsumsq[bc] = r2[0] + r2[1] + r2[2] + r2[3];
  }
}

// ---------------- K2: gate network, counted-vmcnt pipeline (no vmcnt(0) drains) ----------------
// Diagnosis R1-R4: __syncthreads() = "s_waitcnt vmcnt(0) lgkmcnt(0); s_barrier" -> every
// K-chunk force-drains its own prefetch -> each iter costs >= full HBM latency -> fixed
// ~1.7-2.2 TB/s c-ingest no matter the occupancy. Fix (guide T3/T4):
//   * raw s_barrier + lgkmcnt(0) ONLY; vmcnt is compiler-COUNTED per named register set;
//     VMEM issue order pinned (b-frags before the deep prefetch) so no wait drains it.
//   * depth-2 chunk prefetch in registers (chunk k+3 issued at iter k, ~2 iters in flight).
//   * 256B-run staging loads (16 lanes x f32x4 per row); transpose-pack via shfl_xor(16).
//   * 64-l tile, 25KB LDS, grid 1024 -> 4 independent blocks/CU; ds_reads of the current
//     buffer issued BEFORE the barrier -> ONE raw barrier per iteration.
// GEMM1 math identical to the verified R1 kernel: A = c-tile [l][ch] from LDS (m=l),
// B = gw1b rows direct from L2 (n=h), D[l-local=4*kg+reg][h=16*ht+r].
// GEMM2 + epilogue: verified R4 form (Hts aliases the dead A-dbuf; B direct from L2).
__global__ __launch_bounds__(256, 4) void k2_gate(
    const float* __restrict__ cin,
    const unsigned short* __restrict__ gw1b, const unsigned short* __restrict__ gw2b,
    const float* __restrict__ gb1, const float* __restrict__ gb2,
    float* __restrict__ gsum_g, float* __restrict__ csum_g) {
  __shared__ __align__(16) unsigned AsU[2][64 * 36];   // 18432B A dbuf; Hts aliases after GEMM1
  __shared__ float gsum_s[NC], csum_s[NC], gb2_s[NC];
  __shared__ float gb1_s[NH];

  const int t = threadIdx.x;
  const int lane = t & 63;
  const int w = t >> 6;                 // 0..3 (wave owns l-rows [16w,16w+16))
  const int r = lane & 15;
  const int kg = lane >> 4;             // 0..3
  const int b = blockIdx.x >> 7;        // 128 l-tiles per batch
  const int l0 = (blockIdx.x & 127) * 64;

  // staging roles: rr = row-in-group 0..15, q = l-quad 0..15 (256B contiguous per row)
  const int q = t & 15;
  const int rr = t >> 4;
  const int rodd = rr & 1;

  f32x4 acc[8];
#pragma unroll
  for (int i = 0; i < 8; ++i) acc[i] = (f32x4){0.f, 0.f, 0.f, 0.f};

  const float* cstage = cin + (size_t)b * NC * NL + (size_t)rr * NL + l0 + 4 * q;
  const unsigned short* gw1r = gw1b + (size_t)r * NC + kg * 8;   // + ht*16*NC + k*64 (+32)

  f32x4 cvX[4], cvY[4];

#define GLOAD(dst, kch) { \
    _Pragma("unroll") \
    for (int i = 0; i < 4; ++i) \
      dst[i] = __builtin_nontemporal_load( \
          reinterpret_cast<const f32x4*>(cstage + (size_t)((kch) * 64 + 16 * i) * NL)); }

  // transpose-pack chunk into AsU[(kch)&1]: rows pair via shfl_xor(16); csum = plain store
#define STAGE(cv, kch) { \
    unsigned* dst = &AsU[(kch) & 1][0]; \
    _Pragma("unroll") \
    for (int i = 0; i < 4; ++i) { \
      f32x4 v = cv[i]; \
      float s_ = v[0] + v[1] + v[2] + v[3]; \
      s_ += __shfl_xor(s_, 1); s_ += __shfl_xor(s_, 2); \
      s_ += __shfl_xor(s_, 4); s_ += __shfl_xor(s_, 8); \
      if (q == 0) csum_s[(kch) * 64 + 16 * i + rr] = s_; \
      f32x4 ov; \
      ov[0] = __shfl_xor(v[0], 16); ov[1] = __shfl_xor(v[1], 16); \
      ov[2] = __shfl_xor(v[2], 16); ov[3] = __shfl_xor(v[3], 16); \
      const int cp_ = 8 * i + (rr >> 1); \
      const int e_ = 2 * rodd; \
      const unsigned u0_ = rodd ? pack2(ov[e_], v[e_]) : pack2(v[e_], ov[e_]); \
      const unsigned u1_ = rodd ? pack2(ov[e_ + 1], v[e_ + 1]) : pack2(v[e_ + 1], ov[e_ + 1]); \
      dst[(4 * q + e_) * 36 + cp_]     = u0_; \
      dst[(4 * q + e_ + 1) * 36 + cp_] = u1_; \
    } }

  // prologue
  for (int i = t; i < NC; i += 256) { gsum_s[i] = 0.f; gb2_s[i] = gb2[i]; }
  if (t < NH) gb1_s[t] = gb1[t];
  __syncthreads();                       // init visible (outside hot loop; drain OK)
  GLOAD(cvX, 0)
  GLOAD(cvY, 1)
  STAGE(cvX, 0)                          // one full-latency wait, once
  GLOAD(cvX, 2)
  asm volatile("s_waitcnt lgkmcnt(0)" ::: "memory");
  __builtin_amdgcn_s_barrier();
  __builtin_amdgcn_sched_barrier(0);

  // ---------------- GEMM1 main loop: one RAW barrier per chunk, zero vmcnt(0) ----------------
#pragma unroll 1
  for (int k = 0; k < 8; ++k) {
    // 1) current chunk's operands first (oldest VMEM in this iter)
    const unsigned* Abuf = &AsU[k & 1][0];
    const short8 a0 = *reinterpret_cast<const short8*>(&Abuf[(16 * w + r) * 36 + 4 * kg]);
    const short8 a1 = *reinterpret_cast<const short8*>(&Abuf[(16 * w + r) * 36 + 16 + 4 * kg]);
    short8 bfr[16];
#pragma unroll
    for (int ht = 0; ht < 8; ++ht) {
      bfr[2 * ht]     = *reinterpret_cast<const short8*>(gw1r + (size_t)(ht * 16) * NC + k * 64);
      bfr[2 * ht + 1] = *reinterpret_cast<const short8*>(gw1r + (size_t)(ht * 16) * NC + k * 64 + 32);
    }
    __builtin_amdgcn_sched_barrier(0);
    // 2) stage chunk k+1 (vmcnt counted for its cv set; leaves everything younger in flight)
    if (k < 7) {
      if ((k & 1) == 0) { STAGE(cvY, k + 1) } else { STAGE(cvX, k + 1) }
    }
    __builtin_amdgcn_sched_barrier(0);
    // 3) refill that set from chunk k+3 — youngest VMEM; nothing below waits on it
    if (k < 5) {
      if ((k & 1) == 0) { GLOAD(cvY, k + 3) } else { GLOAD(cvX, k + 3) }
    }
    __builtin_amdgcn_sched_barrier(0);
    // 4) MFMA (lgkm wait for a0/a1; counted vmcnt for bfr; prefetch stays in flight)
#pragma unroll
    for (int ht = 0; ht < 8; ++ht)
      acc[ht] = __builtin_amdgcn_mfma_f32_16x16x32_bf16(a0, bfr[2 * ht], acc[ht], 0, 0, 0);
#pragma unroll
    for (int ht = 0; ht < 8; ++ht)
      acc[ht] = __builtin_amdgcn_mfma_f32_16x16x32_bf16(a1, bfr[2 * ht + 1], acc[ht], 0, 0, 0);
    // 5) my LDS writes retired, then RAW barrier (no vmcnt drain)
    asm volatile("s_waitcnt lgkmcnt(0)" ::: "memory");
    __builtin_amdgcn_s_barrier();
    __builtin_amdgcn_sched_barrier(0);
  }

  // epilogue: bias+relu -> Hts (aliases AsU; safe: loop ended on a barrier, all reads done)
  // D map: row = l-local = 4*kg+reg, col = h-in-tile = r
  unsigned short (*Hts)[16][136] = reinterpret_cast<unsigned short (*)[16][136]>(&AsU[0][0]);
#pragma unroll
  for (int ht = 0; ht < 8; ++ht) {
#pragma unroll
    for (int reg = 0; reg < 4; ++reg) {
      const int h = 16 * ht + r;
      Hts[w][4 * kg + reg][h] = f2bf(fmaxf(acc[ht][reg] + gb1_s[h], 0.f));
    }
  }
  // wave-local write->read: per-wave region, in-order DS, no barrier needed
  short8 af[4];
#pragma unroll
  for (int kk = 0; kk < 4; ++kk)
    af[kk] = *reinterpret_cast<const short8*>(&Hts[w][r][32 * kk + 8 * kg]);

  // ---------------- GEMM2: gsum[c] += sigmoid(H^T . gw2[c] + gb2), B direct from L2 ----------
  const unsigned short* gw2r = gw2b + (size_t)r * NH + kg * 8;   // + (cc*64+16*ctt)*NH + kk*32
  for (int cc = 0; cc < 8; ++cc) {
#pragma unroll
    for (int ctt = 0; ctt < 4; ++ctt) {
      f32x4 z = (f32x4){0.f, 0.f, 0.f, 0.f};
#pragma unroll
      for (int kk = 0; kk < 4; ++kk) {
        const short8 bf = *reinterpret_cast<const short8*>(
            gw2r + (size_t)(cc * 64 + 16 * ctt) * NH + kk * 32);
        z = __builtin_amdgcn_mfma_f32_16x16x32_bf16(af[kk], bf, z, 0, 0, 0);
      }
      const float bias = gb2_s[cc * 64 + 16 * ctt + r];
      float s = 0.f;
#pragma unroll
      for (int reg = 0; reg < 4; ++reg)
        s += 1.f / (1.f + __expf(-(z[reg] + bias)));
      s += __shfl_xor(s, 16);
      s += __shfl_xor(s, 32);
      if (lane < 16) atomicAdd(&gsum_s[cc * 64 + 16 * ctt + lane], s);
    }
  }
  __syncthreads();
  for (int i = t; i < NC; i += 256) {
    atomicAdd(&gsum_g[b * NC + i], gsum_s[i]);
    atomicAdd(&csum_g[b * NC + i], csum_s[i]);
  }
}

// ---------------- K3: finalize stats + affine MLP -> per-(b,c) y = A*x + D ----------------
__global__ __launch_bounds__(256) void k3_final(
    const float* __restrict__ xsum, const float* __restrict__ xsumsq,
    const float* __restrict__ csum, const float* __restrict__ gsum,
    const float* __restrict__ mw1, const float* __restrict__ mb1,
    const float* __restrict__ mw2, const float* __restrict__ mb2,
    float* __restrict__ a_arr, float* __restrict__ d_arr) {
  __shared__ __align__(16) float cp[NC];
  __shared__ __align__(16) float hm[NH];
  __shared__ float gbv[2 * NC];
  __shared__ double red[8];
  __shared__ float mu_l_s, sig_l_s;
  const int b = blockIdx.x, t = threadIdx.x;

  double s1 = 0.0, s2 = 0.0;
  for (int c = t; c < NC; c += 256) { s1 += (double)xsum[b * NC + c]; s2 += (double)xsumsq[b * NC + c]; }
  for (int off = 32; off; off >>= 1) { s1 += __shfl_down(s1, off); s2 += __shfl_down(s2, off); }
  if ((t & 63) == 0) { red[(t >> 6) * 2] = s1; red[(t >> 6) * 2 + 1] = s2; }
  for (int c = t; c < NC; c += 256) cp[c] = csum[b * NC + c] * (1.f / NL);
  __syncthreads();
  if (t == 0) {
    double S1 = red[0] + red[2] + red[4] + red[6];
    double S2 = red[1] + red[3] + red[5] + red[7];
    double n = (double)NC * NL;
    double mu = S1 / n;
    double var = S2 / n - mu * mu;
    mu_l_s = (float)mu;
    sig_l_s = (float)sqrt(var + (double)FEPS);
  }
  __syncthreads();
  if (t < NH) {
    const float4* row = reinterpret_cast<const float4*>(mw1 + (size_t)t * NC);
    const float4* cpv = reinterpret_cast<const float4*>(cp);
    float acc = mb1[t];
    for (int i = 0; i < NC / 4; ++i) {
      float4 wv = row[i], xv = cpv[i];
      acc += wv.x * xv.x + wv.y * xv.y + wv.z * xv.z + wv.w * xv.w;
    }
    hm[t] = fmaxf(acc, 0.f);
  }
  __syncthreads();
  for (int o = t; o < 2 * NC; o += 256) {
    const float4* row = reinterpret_cast<const float4*>(mw2 + (size_t)o * NH);
    const float4* hv = reinterpret_cast<const float4*>(hm);
    float acc = mb2[o];
    for (int i = 0; i < NH / 4; ++i) {
      float4 wv = row[i], xv = hv[i];
      acc += wv.x * xv.x + wv.y * xv.y + wv.z * xv.z + wv.w * xv.w;
    }
    gbv[o] = acc;
  }
  __syncthreads();
  const float mu_l = mu_l_s, sig_l = sig_l_s;
  for (int c = t; c < NC; c += 256) {
    float gm = gsum[b * NC + c] * (1.f / NL);
    double mu_c = (double)xsum[b * NC + c] / NL;
    double var_c = (double)xsumsq[b * NC + c] / NL - mu_c * mu_c;
    float sig_c = (float)sqrt(var_c + (double)FEPS);
    float mu = gm * (float)mu_c + (1.f - gm) * mu_l;
    float sg = gm * sig_c + (1.f - gm) * sig_l;
    float gamma = gbv[c], beta = gbv[NC + c];
    float A = (1.f + gamma) / sg;
    a_arr[b * NC + c] = A;
    d_arr[b * NC + c] = beta - A * mu;
  }
}

// ---------------- K4: y = A*x + D, nt stores, imp = sum |y| ----------------
__global__ __launch_bounds__(256) void k4_y(
    const float* __restrict__ x, const float* __restrict__ a_arr,
    const float* __restrict__ d_arr, float* __restrict__ out, float* __restrict__ imp) {
  const int bc = blockIdx.x, t = threadIdx.x;
  const float A = a_arr[bc], D = d_arr[bc];
  const f32x4* xp = reinterpret_cast<const f32x4*>(x + (size_t)bc * NL);
  f32x4* op = reinterpret_cast<f32x4*>(out + (size_t)bc * NL);
  float s = 0.f;
#pragma unroll
  for (int i = 0; i < 8; ++i) {
    f32x4 v = __builtin_nontemporal_load(xp + i * 256 + t);   // last use of x
    f32x4 y;
    y.x = fmaf(A, v.x, D); y.y = fmaf(A, v.y, D);
    y.z = fmaf(A, v.z, D); y.w = fmaf(A, v.w, D);
    s += fabsf(y.x) + fabsf(y.y) + fabsf(y.z) + fabsf(y.w);
    __builtin_nontemporal_store(y, op + i * 256 + t);         // out never re-read
  }
  for (int off = 32; off; off >>= 1) s += __shfl_down(s, off);
  __shared__ float rs[4];
  if ((t & 63) == 0) rs[t >> 6] = s;
  __syncthreads();
  if (t == 0) imp[bc] = rs[0] + rs[1] + rs[2] + rs[3];
}

// ---------------- K5: fused top-k rank (jax.lax.top_k tie semantics) + zero dropped rows ----------------
__global__ __launch_bounds__(256) void k5_apply(
    const float* __restrict__ imp, float* __restrict__ out) {
  const int bc = blockIdx.x;
  const int b = bc >> 9;            // NC = 512
  const int c = bc & (NC - 1);
  const int t = threadIdx.x;
  const float* row = imp + b * NC;
  const float mine = row[c];
  int cnt = 0;
#pragma unroll
  for (int jj = 0; jj < 2; ++jj) {
    const int j = jj * 256 + t;
    const float o = row[j];
    cnt += (o > mine) || (o == mine && j < c);
  }
  for (int off = 32; off; off >>= 1) cnt += __shfl_down(cnt, off);
  __shared__ int rs[4];
  if ((t & 63) == 0) rs[t >> 6] = cnt;
  __syncthreads();
  const int rank = rs[0] + rs[1] + rs[2] + rs[3];   // block-uniform
  if (rank < NKEEP) return;
  f32x4* op = reinterpret_cast<f32x4*>(out + (size_t)bc * NL);
  const f32x4 z = (f32x4){0.f, 0.f, 0.f, 0.f};
#pragma unroll
  for (int i = 0; i < 8; ++i) __builtin_nontemporal_store(z, op + i * 256 + t);
}

extern "C" void kernel_launch(void* const* d_in, const int* in_sizes, int n_in,
                              void* d_out, int out_size, void* d_ws, size_t ws_size,
                              hipStream_t stream) {
  const float* x   = (const float*)d_in[0];
  const float* c   = (const float*)d_in[1];
  const float* gw1 = (const float*)d_in[2];
  const float* gb1 = (const float*)d_in[3];
  const float* gw2 = (const float*)d_in[4];
  const float* gb2 = (const float*)d_in[5];
  const float* mw1 = (const float*)d_in[6];
  const float* mb1 = (const float*)d_in[7];
  const float* mw2 = (const float*)d_in[8];
  const float* mb2 = (const float*)d_in[9];
  float* out = (float*)d_out;
  char* ws = (char*)d_ws;

  unsigned short* gw1b = (unsigned short*)(ws);             // 131072 B
  unsigned short* gw2b = (unsigned short*)(ws + 131072);    // 131072 B
  float* xsum   = (float*)(ws + 262144);
  float* xsumsq = (float*)(ws + 278528);
  float* csum   = (float*)(ws + 294912);
  float* gsum   = (float*)(ws + 311296);
  float* a_arr  = (float*)(ws + 327680);
  float* d_arr  = (float*)(ws + 344064);
  float* imp    = (float*)(ws + 360448);

  k1_xstats<<<NB * NC, 256, 0, stream>>>(x, xsum, xsumsq, gw1, gw2, gw1b, gw2b, csum, gsum);
  k2_gate<<<NB * (NL / 64), 256, 0, stream>>>(c, gw1b, gw2b, gb1, gb2, gsum, csum);
  k3_final<<<NB, 256, 0, stream>>>(xsum, xsumsq, csum, gsum, mw1, mb1, mw2, mb2, a_arr, d_arr);
  k4_y<<<NB * NC, 256, 0, stream>>>(x, a_arr, d_arr, out, imp);
  k5_apply<<<NB * NC, 256, 0, stream>>>(imp, out);
}

// Round 6
// 182.310 us; speedup vs baseline: 1.7457x; 1.7457x over previous
//
#include <hip/hip_runtime.h>
#include <hip/hip_bf16.h>
#include <math.h>

// Problem constants (B,C,L,H fixed by setup_inputs)
#define NB 8
#define NC 512
#define NL 8192
#define NH 128
#define FEPS 1e-5f
#define NKEEP 358   // int(512*0.7)

typedef __attribute__((ext_vector_type(8))) short short8;
typedef __attribute__((ext_vector_type(4))) float f32x4;

__device__ __forceinline__ unsigned short f2bf(float x) {
  unsigned u = __float_as_uint(x);
  return (unsigned short)((u + 0x7fffu + ((u >> 16) & 1u)) >> 16);  // RNE
}
__device__ __forceinline__ unsigned pack2(float a, float b) {
  return (unsigned)f2bf(a) | ((unsigned)f2bf(b) << 16);
}

// ---------------- K0: convert gate weights to bf16, zero accumulators ----------------
__global__ __launch_bounds__(256) void k0_prep(
    const float* __restrict__ gw1, const float* __restrict__ gw2,
    unsigned short* __restrict__ gw1b, unsigned short* __restrict__ gw2b,
    float* __restrict__ csum, float* __restrict__ gsum) {
  int i = blockIdx.x * 256 + threadIdx.x;   // 256*256 = 65536 = H*C = C*H
  gw1b[i] = f2bf(gw1[i]);
  gw2b[i] = f2bf(gw2[i]);
  if (i < NB * NC) { csum[i] = 0.f; gsum[i] = 0.f; }
}

// ---------------- K2: R1-verified gate network + register-resident x-stats side stream ----------------
// Structure = the measured-best round-1 kernel, byte-identical GEMM dataflow:
//   batch b, 128 l-rows, 256 thr = 4 waves; A dbuf in LDS (transposed c), one
//   __syncthreads per K-chunk; GEMM1 B-frags direct from L2; GEMM2 B staged dbuf.
// Addition: k2's memory pipe idles at ~27% duty (66MB HBM / 78us) while old k1 spent
//   ~22us streaming x at full BW. Fold x in as a PURE REGISTER side stream: block owns
//   8 x-rows; per K-chunk each thread issues 8 f32x4 x-loads at iter top (full MFMA
//   phase of flight before the barrier's vmcnt drain) and accumulates pre-barrier.
//   No LDS, no atomics, no change to GEMM1/GEMM2 math or scheduling.
__global__ __launch_bounds__(256, 2) void k2_gate(
    const float* __restrict__ cin, const float* __restrict__ x,
    const unsigned short* __restrict__ gw1b, const unsigned short* __restrict__ gw2b,
    const float* __restrict__ gb1, const float* __restrict__ gb2,
    float* __restrict__ gsum_g, float* __restrict__ csum_g,
    float* __restrict__ xsum, float* __restrict__ xsumsq) {
  __shared__ __align__(16) unsigned AsU[2 * 128 * 36];     // 36864B: GEMM1 A dbuf; GEMM2 reuses as B dbuf (2x16KB)
  __shared__ __align__(16) unsigned short Hts[4][32][136]; // per-wave H^T [l-local][h], pitch 136
  __shared__ float gsum_s[NC], csum_s[NC], gb2_s[NC];
  __shared__ float gb1_s[NH];

  const int t = threadIdx.x;
  const int lane = t & 63;
  const int w = t >> 6;
  const int r = lane & 15;
  const int kg = lane >> 4;
  const int b = blockIdx.x >> 6;
  const int l0 = (blockIdx.x & 63) * 128;

  // staging roles (A): p = chpair 0..31, q = quad-in-pass
  const int p = t >> 3;
  const int q = t & 7;

  f32x4 acc0[8], acc1[8];
#pragma unroll
  for (int i = 0; i < 8; ++i) { acc0[i] = (f32x4){0.f,0.f,0.f,0.f}; acc1[i] = (f32x4){0.f,0.f,0.f,0.f}; }

  const float* cbase = cin + (size_t)b * NC * NL + l0;
  const unsigned short* gw1r = gw1b + (size_t)r * NC + kg * 8;   // + ht*16*NC + k*64 + kk*32

  // x side stream: block owns global rows [blockIdx.x*8, blockIdx.x*8+8); row xr, 32 lanes each
  const int xr = t >> 5;                 // 0..7
  const int xq = t & 31;                 // lane within row
  const float* xrow = x + ((size_t)blockIdx.x * 8 + xr) * NL + 4 * xq;
  f32x4 xv[8];
  float xs1 = 0.f, xs2 = 0.f;

  f32x4 va[4], vb[4];

#define LOADA(kch) { \
    _Pragma("unroll") \
    for (int pass = 0; pass < 4; ++pass) { \
      const float* cp0 = cbase + (size_t)((kch) * 64 + 2 * p) * NL + 32 * pass + 4 * q; \
      va[pass] = __builtin_nontemporal_load(reinterpret_cast<const f32x4*>(cp0)); \
      vb[pass] = __builtin_nontemporal_load(reinterpret_cast<const f32x4*>(cp0 + NL)); \
    } }

#define WRITEA(kch, bufi) { \
    unsigned* dst = AsU + (bufi) * (128 * 36); \
    float sa = 0.f, sb = 0.f; \
    _Pragma("unroll") \
    for (int pass = 0; pass < 4; ++pass) { \
      const int ll = 32 * pass + 4 * q; \
      sa += va[pass].x + va[pass].y + va[pass].z + va[pass].w; \
      sb += vb[pass].x + vb[pass].y + vb[pass].z + vb[pass].w; \
      dst[(ll + 0) * 36 + p] = pack2(va[pass].x, vb[pass].x); \
      dst[(ll + 1) * 36 + p] = pack2(va[pass].y, vb[pass].y); \
      dst[(ll + 2) * 36 + p] = pack2(va[pass].z, vb[pass].z); \
      dst[(ll + 3) * 36 + p] = pack2(va[pass].w, vb[pass].w); \
    } \
    sa += __shfl_xor(sa, 1); sa += __shfl_xor(sa, 2); sa += __shfl_xor(sa, 4); \
    sb += __shfl_xor(sb, 1); sb += __shfl_xor(sb, 2); sb += __shfl_xor(sb, 4); \
    if ((lane & 7) == 0) { \
      atomicAdd(&csum_s[(kch) * 64 + 2 * p],     sa); \
      atomicAdd(&csum_s[(kch) * 64 + 2 * p + 1], sb); \
    } }

#define XLOAD(kch) { \
    _Pragma("unroll") \
    for (int i = 0; i < 8; ++i) \
      xv[i] = *reinterpret_cast<const f32x4*>(xrow + (kch) * 1024 + 128 * i); }

#define XACC() { \
    _Pragma("unroll") \
    for (int i = 0; i < 8; ++i) { \
      f32x4 v_ = xv[i]; \
      xs1 += v_.x + v_.y + v_.z + v_.w; \
      xs2 += v_.x * v_.x + v_.y * v_.y + v_.z * v_.z + v_.w * v_.w; \
    } }

  // prologue: issue chunk-0 loads early, init smem, barrier (init vs csum atomics), stage chunk 0
  LOADA(0)
  for (int i = t; i < NC; i += 256) { gsum_s[i] = 0.f; csum_s[i] = 0.f; gb2_s[i] = gb2[i]; }
  if (t < NH) gb1_s[t] = gb1[t];
  __syncthreads();
  WRITEA(0, 0)
  __syncthreads();

  // ---------------- GEMM1 main loop: one barrier per K-chunk (R1-verified) ----------------
  for (int k = 0; k < 8; ++k) {
    const int cur = k & 1;
    XLOAD(k)                              // x side stream: full MFMA phase of flight
    if (k < 7) LOADA(k + 1)               // in flight across the whole MFMA phase
    const unsigned* Abuf = AsU + cur * (128 * 36);
#pragma unroll
    for (int kk = 0; kk < 2; ++kk) {
      const short8 a0 = *reinterpret_cast<const short8*>(&Abuf[(32 * w + r)      * 36 + 16 * kk + 4 * kg]);
      const short8 a1 = *reinterpret_cast<const short8*>(&Abuf[(32 * w + 16 + r) * 36 + 16 * kk + 4 * kg]);
#pragma unroll
      for (int ht = 0; ht < 8; ++ht) {
        // B-frag straight from L2: gw1b[16*ht+r][k*64 + kk*32 + kg*8 .. +8)
        const short8 bf = *reinterpret_cast<const short8*>(
            gw1r + (size_t)(ht * 16) * NC + k * 64 + kk * 32);
        acc0[ht] = __builtin_amdgcn_mfma_f32_16x16x32_bf16(a0, bf, acc0[ht], 0, 0, 0);
        acc1[ht] = __builtin_amdgcn_mfma_f32_16x16x32_bf16(a1, bf, acc1[ht], 0, 0, 0);
      }
    }
    if (k < 7) WRITEA(k + 1, cur ^ 1)     // counted vmcnt wait lands here, after MFMAs issued
    XACC()                                // xv already drained by WRITEA's wait (older in queue)
    __syncthreads();
  }

  // x-stats finalize: reduce over the 32 lanes of each row (rows are 32-lane aligned)
  for (int off = 16; off; off >>= 1) { xs1 += __shfl_down(xs1, off); xs2 += __shfl_down(xs2, off); }
  if (xq == 0) {
    xsum[blockIdx.x * 8 + xr]   = xs1;
    xsumsq[blockIdx.x * 8 + xr] = xs2;
  }

  // epilogue: bias+relu -> Hts (D map: col=lane&15, row=(lane>>4)*4+reg)
#pragma unroll
  for (int ht = 0; ht < 8; ++ht) {
    const float bias = gb1_s[16 * ht + r];
#pragma unroll
    for (int reg = 0; reg < 4; ++reg) {
      Hts[w][4 * kg + reg][16 * ht + r]      = f2bf(fmaxf(acc0[ht][reg] + bias, 0.f));
      Hts[w][16 + 4 * kg + reg][16 * ht + r] = f2bf(fmaxf(acc1[ht][reg] + bias, 0.f));
    }
  }
  // wave-local write->read: per-wave DS ordering, no barrier needed
  short8 af0[4], af1[4];
#pragma unroll
  for (int kk = 0; kk < 4; ++kk) {
    af0[kk] = *reinterpret_cast<const short8*>(&Hts[w][r][32 * kk + 8 * kg]);
    af1[kk] = *reinterpret_cast<const short8*>(&Hts[w][16 + r][32 * kk + 8 * kg]);
  }

  // ---------------- GEMM2: gsum[c] += sigmoid(H^T . gw2[c] + gb2), B dbuf in AsU space ----------------
  unsigned short* Bs2 = reinterpret_cast<unsigned short*>(AsU);
  const int crow = lane >> 4;    // B2: row offset 0..3
  const int bs2  = lane & 15;    // B2: slot 0..15
  short8 bv[4];

#define LOADB2(ccn) { \
    _Pragma("unroll") \
    for (int j = 0; j < 4; ++j) { \
      const int cl = 16 * w + 4 * j + crow; \
      bv[j] = *reinterpret_cast<const short8*>(gw2b + (size_t)((ccn) * 64 + cl) * NH + bs2 * 8); \
    } }
#define WRITEB2(ccn) { \
    unsigned short* dstb = Bs2 + ((ccn) & 1) * 8192; \
    _Pragma("unroll") \
    for (int j = 0; j < 4; ++j) { \
      const int cl = 16 * w + 4 * j + crow; \
      *reinterpret_cast<short8*>(&dstb[cl * 128 + ((bs2 ^ (cl & 7)) * 8)]) = bv[j]; \
    } }

  LOADB2(0)
  WRITEB2(0)                      // safe: all waves past GEMM1's final barrier
  __syncthreads();
  for (int cc = 0; cc < 8; ++cc) {
    if (cc < 7) LOADB2(cc + 1)
    const unsigned short* Bbuf = Bs2 + (cc & 1) * 8192;
#pragma unroll
    for (int ctt = 0; ctt < 4; ++ctt) {
      f32x4 z0 = (f32x4){0.f,0.f,0.f,0.f}, z1 = (f32x4){0.f,0.f,0.f,0.f};
#pragma unroll
      for (int kk = 0; kk < 4; ++kk) {
        const short8 bf = *reinterpret_cast<const short8*>(
            &Bbuf[(16 * ctt + r) * 128 + (((4 * kk + kg) ^ (r & 7)) * 8)]);
        z0 = __builtin_amdgcn_mfma_f32_16x16x32_bf16(af0[kk], bf, z0, 0, 0, 0);
        z1 = __builtin_amdgcn_mfma_f32_16x16x32_bf16(af1[kk], bf, z1, 0, 0, 0);
      }
      const float bias = gb2_s[cc * 64 + 16 * ctt + r];
      float s = 0.f;
#pragma unroll
      for (int reg = 0; reg < 4; ++reg) {
        s += 1.f / (1.f + __expf(-(z0[reg] + bias)));
        s += 1.f / (1.f + __expf(-(z1[reg] + bias)));
      }
      s += __shfl_xor(s, 16);
      s += __shfl_xor(s, 32);
      if (lane < 16) atomicAdd(&gsum_s[cc * 64 + 16 * ctt + lane], s);
    }
    if (cc < 7) WRITEB2(cc + 1)
    __syncthreads();
  }
  for (int i = t; i < NC; i += 256) {
    atomicAdd(&gsum_g[b * NC + i], gsum_s[i]);
    atomicAdd(&csum_g[b * NC + i], csum_s[i]);
  }
}

// ---------------- K3: finalize stats + affine MLP -> per-(b,c) y = A*x + D ----------------
__global__ __launch_bounds__(256) void k3_final(
    const float* __restrict__ xsum, const float* __restrict__ xsumsq,
    const float* __restrict__ csum, const float* __restrict__ gsum,
    const float* __restrict__ mw1, const float* __restrict__ mb1,
    const float* __restrict__ mw2, const float* __restrict__ mb2,
    float* __restrict__ a_arr, float* __restrict__ d_arr) {
  __shared__ __align__(16) float cp[NC];
  __shared__ __align__(16) float hm[NH];
  __shared__ float gbv[2 * NC];
  __shared__ double red[8];
  __shared__ float mu_l_s, sig_l_s;
  const int b = blockIdx.x, t = threadIdx.x;

  double s1 = 0.0, s2 = 0.0;
  for (int c = t; c < NC; c += 256) { s1 += (double)xsum[b * NC + c]; s2 += (double)xsumsq[b * NC + c]; }
  for (int off = 32; off; off >>= 1) { s1 += __shfl_down(s1, off); s2 += __shfl_down(s2, off); }
  if ((t & 63) == 0) { red[(t >> 6) * 2] = s1; red[(t >> 6) * 2 + 1] = s2; }
  for (int c = t; c < NC; c += 256) cp[c] = csum[b * NC + c] * (1.f / NL);
  __syncthreads();
  if (t == 0) {
    double S1 = red[0] + red[2] + red[4] + red[6];
    double S2 = red[1] + red[3] + red[5] + red[7];
    double n = (double)NC * NL;
    double mu = S1 / n;
    double var = S2 / n - mu * mu;
    mu_l_s = (float)mu;
    sig_l_s = (float)sqrt(var + (double)FEPS);
  }
  __syncthreads();
  if (t < NH) {
    const float4* row = reinterpret_cast<const float4*>(mw1 + (size_t)t * NC);
    const float4* cpv = reinterpret_cast<const float4*>(cp);
    float acc = mb1[t];
    for (int i = 0; i < NC / 4; ++i) {
      float4 wv = row[i], xv = cpv[i];
      acc += wv.x * xv.x + wv.y * xv.y + wv.z * xv.z + wv.w * xv.w;
    }
    hm[t] = fmaxf(acc, 0.f);
  }
  __syncthreads();
  for (int o = t; o < 2 * NC; o += 256) {
    const float4* row = reinterpret_cast<const float4*>(mw2 + (size_t)o * NH);
    const float4* hv = reinterpret_cast<const float4*>(hm);
    float acc = mb2[o];
    for (int i = 0; i < NH / 4; ++i) {
      float4 wv = row[i], xv = hv[i];
      acc += wv.x * xv.x + wv.y * xv.y + wv.z * xv.z + wv.w * xv.w;
    }
    gbv[o] = acc;
  }
  __syncthreads();
  const float mu_l = mu_l_s, sig_l = sig_l_s;
  for (int c = t; c < NC; c += 256) {
    float gm = gsum[b * NC + c] * (1.f / NL);
    double mu_c = (double)xsum[b * NC + c] / NL;
    double var_c = (double)xsumsq[b * NC + c] / NL - mu_c * mu_c;
    float sig_c = (float)sqrt(var_c + (double)FEPS);
    float mu = gm * (float)mu_c + (1.f - gm) * mu_l;
    float sg = gm * sig_c + (1.f - gm) * sig_l;
    float gamma = gbv[c], beta = gbv[NC + c];
    float A = (1.f + gamma) / sg;
    a_arr[b * NC + c] = A;
    d_arr[b * NC + c] = beta - A * mu;
  }
}

// ---------------- K4: y = A*x + D, nt stores, imp = sum |y| ----------------
__global__ __launch_bounds__(256) void k4_y(
    const float* __restrict__ x, const float* __restrict__ a_arr,
    const float* __restrict__ d_arr, float* __restrict__ out, float* __restrict__ imp) {
  const int bc = blockIdx.x, t = threadIdx.x;
  const float A = a_arr[bc], D = d_arr[bc];
  const f32x4* xp = reinterpret_cast<const f32x4*>(x + (size_t)bc * NL);
  f32x4* op = reinterpret_cast<f32x4*>(out + (size_t)bc * NL);
  float s = 0.f;
#pragma unroll
  for (int i = 0; i < 8; ++i) {
    f32x4 v = __builtin_nontemporal_load(xp + i * 256 + t);   // last use of x
    f32x4 y;
    y.x = fmaf(A, v.x, D); y.y = fmaf(A, v.y, D);
    y.z = fmaf(A, v.z, D); y.w = fmaf(A, v.w, D);
    s += fabsf(y.x) + fabsf(y.y) + fabsf(y.z) + fabsf(y.w);
    __builtin_nontemporal_store(y, op + i * 256 + t);         // out never re-read
  }
  for (int off = 32; off; off >>= 1) s += __shfl_down(s, off);
  __shared__ float rs[4];
  if ((t & 63) == 0) rs[t >> 6] = s;
  __syncthreads();
  if (t == 0) imp[bc] = rs[0] + rs[1] + rs[2] + rs[3];
}

// ---------------- K5: fused top-k rank (jax.lax.top_k tie semantics) + zero dropped rows ----------------
__global__ __launch_bounds__(256) void k5_apply(
    const float* __restrict__ imp, float* __restrict__ out) {
  const int bc = blockIdx.x;
  const int b = bc >> 9;            // NC = 512
  const int c = bc & (NC - 1);
  const int t = threadIdx.x;
  const float* row = imp + b * NC;
  const float mine = row[c];
  int cnt = 0;
#pragma unroll
  for (int jj = 0; jj < 2; ++jj) {
    const int j = jj * 256 + t;
    const float o = row[j];
    cnt += (o > mine) || (o == mine && j < c);
  }
  for (int off = 32; off; off >>= 1) cnt += __shfl_down(cnt, off);
  __shared__ int rs[4];
  if ((t & 63) == 0) rs[t >> 6] = cnt;
  __syncthreads();
  const int rank = rs[0] + rs[1] + rs[2] + rs[3];   // block-uniform
  if (rank < NKEEP) return;
  f32x4* op = reinterpret_cast<f32x4*>(out + (size_t)bc * NL);
  const f32x4 z = (f32x4){0.f, 0.f, 0.f, 0.f};
#pragma unroll
  for (int i = 0; i < 8; ++i) __builtin_nontemporal_store(z, op + i * 256 + t);
}

extern "C" void kernel_launch(void* const* d_in, const int* in_sizes, int n_in,
                              void* d_out, int out_size, void* d_ws, size_t ws_size,
                              hipStream_t stream) {
  const float* x   = (const float*)d_in[0];
  const float* c   = (const float*)d_in[1];
  const float* gw1 = (const float*)d_in[2];
  const float* gb1 = (const float*)d_in[3];
  const float* gw2 = (const float*)d_in[4];
  const float* gb2 = (const float*)d_in[5];
  const float* mw1 = (const float*)d_in[6];
  const float* mb1 = (const float*)d_in[7];
  const float* mw2 = (const float*)d_in[8];
  const float* mb2 = (const float*)d_in[9];
  float* out = (float*)d_out;
  char* ws = (char*)d_ws;

  unsigned short* gw1b = (unsigned short*)(ws);             // 131072 B
  unsigned short* gw2b = (unsigned short*)(ws + 131072);    // 131072 B
  float* xsum   = (float*)(ws + 262144);
  float* xsumsq = (float*)(ws + 278528);
  float* csum   = (float*)(ws + 294912);
  float* gsum   = (float*)(ws + 311296);
  float* a_arr  = (float*)(ws + 327680);
  float* d_arr  = (float*)(ws + 344064);
  float* imp    = (float*)(ws + 360448);

  k0_prep<<<256, 256, 0, stream>>>(gw1, gw2, gw1b, gw2b, csum, gsum);
  k2_gate<<<NB * (NL / 128), 256, 0, stream>>>(c, x, gw1b, gw2b, gb1, gb2, gsum, csum, xsum, xsumsq);
  k3_final<<<NB, 256, 0, stream>>>(xsum, xsumsq, csum, gsum, mw1, mb1, mw2, mb2, a_arr, d_arr);
  k4_y<<<NB * NC, 256, 0, stream>>>(x, a_arr, d_arr, out, imp);
  k5_apply<<<NB * NC, 256, 0, stream>>>(imp, out);
}

// Round 7
// 170.869 us; speedup vs baseline: 1.8626x; 1.0670x over previous
//
#include <hip/hip_runtime.h>
#include <hip/hip_bf16.h>
#include <math.h>

// Problem constants (B,C,L,H fixed by setup_inputs)
#define NB 8
#define NC 512
#define NL 8192
#define NH 128
#define FEPS 1e-5f
#define NKEEP 358   // int(512*0.7)

typedef __attribute__((ext_vector_type(8))) short short8;
typedef __attribute__((ext_vector_type(4))) float f32x4;

__device__ __forceinline__ unsigned short f2bf(float x) {
  unsigned u = __float_as_uint(x);
  return (unsigned short)((u + 0x7fffu + ((u >> 16) & 1u)) >> 16);  // RNE
}
__device__ __forceinline__ unsigned pack2(float a, float b) {
  return (unsigned)f2bf(a) | ((unsigned)f2bf(b) << 16);
}

// ---------------- K1: per-(b,c) sum/sumsq of x over L; blocks 0..255 also prep weights ----------------
// Near-roofline streamer (~5.4 TB/s measured): contiguous float4, no barriers in the stream.
__global__ __launch_bounds__(256) void k1_xstats(
    const float* __restrict__ x, float* __restrict__ xsum, float* __restrict__ xsumsq,
    const float* __restrict__ gw1, const float* __restrict__ gw2,
    unsigned short* __restrict__ gw1b, unsigned short* __restrict__ gw2b,
    float* __restrict__ csum, float* __restrict__ gsum) {
  const int bc = blockIdx.x;
  const int t = threadIdx.x;
  if (bc < 256) {                       // fused weight prep (65536 = H*C = C*H elems)
    const int i = bc * 256 + t;
    gw1b[i] = f2bf(gw1[i]);
    gw2b[i] = f2bf(gw2[i]);
    if (i < NB * NC) { csum[i] = 0.f; gsum[i] = 0.f; }
  }
  const float4* xp = reinterpret_cast<const float4*>(x + (size_t)bc * NL);
  float s1 = 0.f, s2 = 0.f;
#pragma unroll
  for (int i = 0; i < 8; ++i) {
    float4 v = xp[i * 256 + t];
    s1 += v.x + v.y + v.z + v.w;
    s2 += v.x * v.x + v.y * v.y + v.z * v.z + v.w * v.w;
  }
  for (int off = 32; off; off >>= 1) { s1 += __shfl_down(s1, off); s2 += __shfl_down(s2, off); }
  __shared__ float r1[4], r2[4];
  if ((t & 63) == 0) { r1[t >> 6] = s1; r2[t >> 6] = s2; }
  __syncthreads();
  if (t == 0) {
    xsum[bc]   = r1[0] + r1[1] + r1[2] + r1[3];
    xsumsq[bc] = r2[0] + r2[1] + r2[2] + r2[3];
  }
}

// ---------------- K2: R1 gate network + true deep prefetch (drain mechanism fixed) ----------------
// Structure/math/layout = the measured-best round-1 kernel, byte-identical GEMM dataflow.
// Drain diagnosis (R1-R6): inline B-frag loads inside the MFMA loop are YOUNGER than the
// A-prefetch in the in-order vmcnt queue; consuming them forces vmcnt~0 -> the prefetch is
// drained mid-iteration, every iteration; __syncthreads (vmcnt(0)+barrier) drains the rest.
// Load-to-use distance never exceeded a fraction of an iteration -> fixed ~1.7 TB/s ingest.
// Fix (3 coupled pieces, everything else untouched):
//   1. hoist all 16 B-frags to iteration top, BEFORE the deep prefetch (MFMA waits count
//      only bfr, never the prefetch);
//   2. depth-2 register staging: LOADA(k+2) at iter k, consumed by WRITEA(k+2) at iter k+1
//      -> one full iteration of flight;
//   3. raw s_barrier + lgkmcnt(0) in the GEMM1 loop (no vmcnt(0) drain); sched_barrier(0)
//      pins region order. lgkmcnt(0) retires each wave's ds_reads AND ds_writes before the
//      barrier, so buffer overwrite hazards are covered.
__global__ __launch_bounds__(256, 2) void k2_gate(
    const float* __restrict__ cin,
    const unsigned short* __restrict__ gw1b, const unsigned short* __restrict__ gw2b,
    const float* __restrict__ gb1, const float* __restrict__ gb2,
    float* __restrict__ gsum_g, float* __restrict__ csum_g) {
  __shared__ __align__(16) unsigned AsU[2 * 128 * 36];     // 36864B: GEMM1 A dbuf; GEMM2 reuses as B dbuf (2x16KB)
  __shared__ __align__(16) unsigned short Hts[4][32][136]; // per-wave H^T [l-local][h], pitch 136
  __shared__ float gsum_s[NC], csum_s[NC], gb2_s[NC];
  __shared__ float gb1_s[NH];

  const int t = threadIdx.x;
  const int lane = t & 63;
  const int w = t >> 6;
  const int r = lane & 15;
  const int kg = lane >> 4;
  const int b = blockIdx.x >> 6;
  const int l0 = (blockIdx.x & 63) * 128;

  // staging roles (A): p = chpair 0..31, q = quad-in-pass
  const int p = t >> 3;
  const int q = t & 7;

  f32x4 acc0[8], acc1[8];
#pragma unroll
  for (int i = 0; i < 8; ++i) { acc0[i] = (f32x4){0.f,0.f,0.f,0.f}; acc1[i] = (f32x4){0.f,0.f,0.f,0.f}; }

  const float* cbase = cin + (size_t)b * NC * NL + l0;
  const unsigned short* gw1r = gw1b + (size_t)r * NC + kg * 8;   // + ht*16*NC + k*64 + kk*32

  // two named staging register sets: A holds even chunks, B holds odd chunks (rule-#20 static)
  f32x4 vaA[4], vbA[4], vaB[4], vbB[4];

#define LOADA(dA, dB, kch) { \
    _Pragma("unroll") \
    for (int pass = 0; pass < 4; ++pass) { \
      const float* cp0 = cbase + (size_t)((kch) * 64 + 2 * p) * NL + 32 * pass + 4 * q; \
      dA[pass] = __builtin_nontemporal_load(reinterpret_cast<const f32x4*>(cp0)); \
      dB[pass] = __builtin_nontemporal_load(reinterpret_cast<const f32x4*>(cp0 + NL)); \
    } }

#define WRITEA(sA, sB, kch, bufi) { \
    unsigned* dst = AsU + (bufi) * (128 * 36); \
    float sa = 0.f, sb = 0.f; \
    _Pragma("unroll") \
    for (int pass = 0; pass < 4; ++pass) { \
      const int ll = 32 * pass + 4 * q; \
      sa += sA[pass].x + sA[pass].y + sA[pass].z + sA[pass].w; \
      sb += sB[pass].x + sB[pass].y + sB[pass].z + sB[pass].w; \
      dst[(ll + 0) * 36 + p] = pack2(sA[pass].x, sB[pass].x); \
      dst[(ll + 1) * 36 + p] = pack2(sA[pass].y, sB[pass].y); \
      dst[(ll + 2) * 36 + p] = pack2(sA[pass].z, sB[pass].z); \
      dst[(ll + 3) * 36 + p] = pack2(sA[pass].w, sB[pass].w); \
    } \
    sa += __shfl_xor(sa, 1); sa += __shfl_xor(sa, 2); sa += __shfl_xor(sa, 4); \
    sb += __shfl_xor(sb, 1); sb += __shfl_xor(sb, 2); sb += __shfl_xor(sb, 4); \
    if ((lane & 7) == 0) { \
      atomicAdd(&csum_s[(kch) * 64 + 2 * p],     sa); \
      atomicAdd(&csum_s[(kch) * 64 + 2 * p + 1], sb); \
    } }

  // prologue: chunks 0 and 1 in flight, init smem, full drain ONCE, stage chunk 0
  LOADA(vaA, vbA, 0)
  LOADA(vaB, vbB, 1)
  for (int i = t; i < NC; i += 256) { gsum_s[i] = 0.f; csum_s[i] = 0.f; gb2_s[i] = gb2[i]; }
  if (t < NH) gb1_s[t] = gb1[t];
  __syncthreads();                      // one-time vmcnt drain, outside the hot loop
  WRITEA(vaA, vbA, 0, 0)
  asm volatile("s_waitcnt lgkmcnt(0)" ::: "memory");
  __builtin_amdgcn_s_barrier();
  __builtin_amdgcn_sched_barrier(0);

  // ---------------- GEMM1 main loop: raw barrier, prefetch never drained ----------------
  for (int k = 0; k < 8; ++k) {
    const unsigned* Abuf = AsU + (k & 1) * (128 * 36);
    // 1) all B-frags for this chunk (L2), BEFORE the deep prefetch -> MFMA waits stop here
    short8 bfr[16];
#pragma unroll
    for (int ht = 0; ht < 8; ++ht) {
      bfr[2 * ht]     = *reinterpret_cast<const short8*>(gw1r + (size_t)(ht * 16) * NC + k * 64);
      bfr[2 * ht + 1] = *reinterpret_cast<const short8*>(gw1r + (size_t)(ht * 16) * NC + k * 64 + 32);
    }
    // 2) A-frags from LDS (written iter k-1, visible via barrier)
    short8 a0[2], a1[2];
#pragma unroll
    for (int kk = 0; kk < 2; ++kk) {
      a0[kk] = *reinterpret_cast<const short8*>(&Abuf[(32 * w + r)      * 36 + 16 * kk + 4 * kg]);
      a1[kk] = *reinterpret_cast<const short8*>(&Abuf[(32 * w + 16 + r) * 36 + 16 * kk + 4 * kg]);
    }
    __builtin_amdgcn_sched_barrier(0);
    // 3) stage chunk k+1 (counted vmcnt on its reg set; loads had a full iteration of flight)
    if (k < 7) {
      if ((k & 1) == 0) { WRITEA(vaB, vbB, k + 1, 1) } else { WRITEA(vaA, vbA, k + 1, 0) }
    }
    __builtin_amdgcn_sched_barrier(0);
    // 4) deep prefetch chunk k+2 into the freed set — youngest VMEM; nothing below waits on it
    if (k < 6) {
      if ((k & 1) == 0) { LOADA(vaA, vbA, k + 2) } else { LOADA(vaB, vbB, k + 2) }
    }
    __builtin_amdgcn_sched_barrier(0);
    // 5) MFMA: waits cover bfr (older than prefetch) and a-frags (lgkm) only
#pragma unroll
    for (int kk = 0; kk < 2; ++kk) {
#pragma unroll
      for (int ht = 0; ht < 8; ++ht) {
        acc0[ht] = __builtin_amdgcn_mfma_f32_16x16x32_bf16(a0[kk], bfr[2 * ht + kk], acc0[ht], 0, 0, 0);
        acc1[ht] = __builtin_amdgcn_mfma_f32_16x16x32_bf16(a1[kk], bfr[2 * ht + kk], acc1[ht], 0, 0, 0);
      }
    }
    // 6) publish my DS ops, raw barrier — NO vmcnt drain
    __builtin_amdgcn_sched_barrier(0);
    asm volatile("s_waitcnt lgkmcnt(0)" ::: "memory");
    __builtin_amdgcn_s_barrier();
    __builtin_amdgcn_sched_barrier(0);
  }

  // epilogue: bias+relu -> Hts (D map: col=lane&15, row=(lane>>4)*4+reg)
#pragma unroll
  for (int ht = 0; ht < 8; ++ht) {
    const float bias = gb1_s[16 * ht + r];
#pragma unroll
    for (int reg = 0; reg < 4; ++reg) {
      Hts[w][4 * kg + reg][16 * ht + r]      = f2bf(fmaxf(acc0[ht][reg] + bias, 0.f));
      Hts[w][16 + 4 * kg + reg][16 * ht + r] = f2bf(fmaxf(acc1[ht][reg] + bias, 0.f));
    }
  }
  // wave-local write->read: per-wave DS ordering, no barrier needed
  short8 af0[4], af1[4];
#pragma unroll
  for (int kk = 0; kk < 4; ++kk) {
    af0[kk] = *reinterpret_cast<const short8*>(&Hts[w][r][32 * kk + 8 * kg]);
    af1[kk] = *reinterpret_cast<const short8*>(&Hts[w][16 + r][32 * kk + 8 * kg]);
  }

  // ---------------- GEMM2: gsum[c] += sigmoid(H^T . gw2[c] + gb2), B dbuf in AsU space ----------------
  unsigned short* Bs2 = reinterpret_cast<unsigned short*>(AsU);
  const int crow = lane >> 4;    // B2: row offset 0..3
  const int bs2  = lane & 15;    // B2: slot 0..15
  short8 bv[4];

#define LOADB2(ccn) { \
    _Pragma("unroll") \
    for (int j = 0; j < 4; ++j) { \
      const int cl = 16 * w + 4 * j + crow; \
      bv[j] = *reinterpret_cast<const short8*>(gw2b + (size_t)((ccn) * 64 + cl) * NH + bs2 * 8); \
    } }
#define WRITEB2(ccn) { \
    unsigned short* dstb = Bs2 + ((ccn) & 1) * 8192; \
    _Pragma("unroll") \
    for (int j = 0; j < 4; ++j) { \
      const int cl = 16 * w + 4 * j + crow; \
      *reinterpret_cast<short8*>(&dstb[cl * 128 + ((bs2 ^ (cl & 7)) * 8)]) = bv[j]; \
    } }

  LOADB2(0)
  WRITEB2(0)                      // safe: all waves past GEMM1's final barrier
  __syncthreads();
  for (int cc = 0; cc < 8; ++cc) {
    if (cc < 7) LOADB2(cc + 1)
    const unsigned short* Bbuf = Bs2 + (cc & 1) * 8192;
#pragma unroll
    for (int ctt = 0; ctt < 4; ++ctt) {
      f32x4 z0 = (f32x4){0.f,0.f,0.f,0.f}, z1 = (f32x4){0.f,0.f,0.f,0.f};
#pragma unroll
      for (int kk = 0; kk < 4; ++kk) {
        const short8 bf = *reinterpret_cast<const short8*>(
            &Bbuf[(16 * ctt + r) * 128 + (((4 * kk + kg) ^ (r & 7)) * 8)]);
        z0 = __builtin_amdgcn_mfma_f32_16x16x32_bf16(af0[kk], bf, z0, 0, 0, 0);
        z1 = __builtin_amdgcn_mfma_f32_16x16x32_bf16(af1[kk], bf, z1, 0, 0, 0);
      }
      const float bias = gb2_s[cc * 64 + 16 * ctt + r];
      float s = 0.f;
#pragma unroll
      for (int reg = 0; reg < 4; ++reg) {
        s += 1.f / (1.f + __expf(-(z0[reg] + bias)));
        s += 1.f / (1.f + __expf(-(z1[reg] + bias)));
      }
      s += __shfl_xor(s, 16);
      s += __shfl_xor(s, 32);
      if (lane < 16) atomicAdd(&gsum_s[cc * 64 + 16 * ctt + lane], s);
    }
    if (cc < 7) WRITEB2(cc + 1)
    __syncthreads();
  }
  for (int i = t; i < NC; i += 256) {
    atomicAdd(&gsum_g[b * NC + i], gsum_s[i]);
    atomicAdd(&csum_g[b * NC + i], csum_s[i]);
  }
}

// ---------------- K3: finalize stats + affine MLP -> per-(b,c) y = A*x + D ----------------
__global__ __launch_bounds__(256) void k3_final(
    const float* __restrict__ xsum, const float* __restrict__ xsumsq,
    const float* __restrict__ csum, const float* __restrict__ gsum,
    const float* __restrict__ mw1, const float* __restrict__ mb1,
    const float* __restrict__ mw2, const float* __restrict__ mb2,
    float* __restrict__ a_arr, float* __restrict__ d_arr) {
  __shared__ __align__(16) float cp[NC];
  __shared__ __align__(16) float hm[NH];
  __shared__ float gbv[2 * NC];
  __shared__ double red[8];
  __shared__ float mu_l_s, sig_l_s;
  const int b = blockIdx.x, t = threadIdx.x;

  double s1 = 0.0, s2 = 0.0;
  for (int c = t; c < NC; c += 256) { s1 += (double)xsum[b * NC + c]; s2 += (double)xsumsq[b * NC + c]; }
  for (int off = 32; off; off >>= 1) { s1 += __shfl_down(s1, off); s2 += __shfl_down(s2, off); }
  if ((t & 63) == 0) { red[(t >> 6) * 2] = s1; red[(t >> 6) * 2 + 1] = s2; }
  for (int c = t; c < NC; c += 256) cp[c] = csum[b * NC + c] * (1.f / NL);
  __syncthreads();
  if (t == 0) {
    double S1 = red[0] + red[2] + red[4] + red[6];
    double S2 = red[1] + red[3] + red[5] + red[7];
    double n = (double)NC * NL;
    double mu = S1 / n;
    double var = S2 / n - mu * mu;
    mu_l_s = (float)mu;
    sig_l_s = (float)sqrt(var + (double)FEPS);
  }
  __syncthreads();
  if (t < NH) {
    const float4* row = reinterpret_cast<const float4*>(mw1 + (size_t)t * NC);
    const float4* cpv = reinterpret_cast<const float4*>(cp);
    float acc = mb1[t];
    for (int i = 0; i < NC / 4; ++i) {
      float4 wv = row[i], xv = cpv[i];
      acc += wv.x * xv.x + wv.y * xv.y + wv.z * xv.z + wv.w * xv.w;
    }
    hm[t] = fmaxf(acc, 0.f);
  }
  __syncthreads();
  for (int o = t; o < 2 * NC; o += 256) {
    const float4* row = reinterpret_cast<const float4*>(mw2 + (size_t)o * NH);
    const float4* hv = reinterpret_cast<const float4*>(hm);
    float acc = mb2[o];
    for (int i = 0; i < NH / 4; ++i) {
      float4 wv = row[i], xv = hv[i];
      acc += wv.x * xv.x + wv.y * xv.y + wv.z * xv.z + wv.w * xv.w;
    }
    gbv[o] = acc;
  }
  __syncthreads();
  const float mu_l = mu_l_s, sig_l = sig_l_s;
  for (int c = t; c < NC; c += 256) {
    float gm = gsum[b * NC + c] * (1.f / NL);
    double mu_c = (double)xsum[b * NC + c] / NL;
    double var_c = (double)xsumsq[b * NC + c] / NL - mu_c * mu_c;
    float sig_c = (float)sqrt(var_c + (double)FEPS);
    float mu = gm * (float)mu_c + (1.f - gm) * mu_l;
    float sg = gm * sig_c + (1.f - gm) * sig_l;
    float gamma = gbv[c], beta = gbv[NC + c];
    float A = (1.f + gamma) / sg;
    a_arr[b * NC + c] = A;
    d_arr[b * NC + c] = beta - A * mu;
  }
}

// ---------------- K4: y = A*x + D, nt stores, imp = sum |y| ----------------
__global__ __launch_bounds__(256) void k4_y(
    const float* __restrict__ x, const float* __restrict__ a_arr,
    const float* __restrict__ d_arr, float* __restrict__ out, float* __restrict__ imp) {
  const int bc = blockIdx.x, t = threadIdx.x;
  const float A = a_arr[bc], D = d_arr[bc];
  const f32x4* xp = reinterpret_cast<const f32x4*>(x + (size_t)bc * NL);
  f32x4* op = reinterpret_cast<f32x4*>(out + (size_t)bc * NL);
  float s = 0.f;
#pragma unroll
  for (int i = 0; i < 8; ++i) {
    f32x4 v = __builtin_nontemporal_load(xp + i * 256 + t);   // last use of x
    f32x4 y;
    y.x = fmaf(A, v.x, D); y.y = fmaf(A, v.y, D);
    y.z = fmaf(A, v.z, D); y.w = fmaf(A, v.w, D);
    s += fabsf(y.x) + fabsf(y.y) + fabsf(y.z) + fabsf(y.w);
    __builtin_nontemporal_store(y, op + i * 256 + t);         // out never re-read
  }
  for (int off = 32; off; off >>= 1) s += __shfl_down(s, off);
  __shared__ float rs[4];
  if ((t & 63) == 0) rs[t >> 6] = s;
  __syncthreads();
  if (t == 0) imp[bc] = rs[0] + rs[1] + rs[2] + rs[3];
}

// ---------------- K5: fused top-k rank (jax.lax.top_k tie semantics) + zero dropped rows ----------------
__global__ __launch_bounds__(256) void k5_apply(
    const float* __restrict__ imp, float* __restrict__ out) {
  const int bc = blockIdx.x;
  const int b = bc >> 9;            // NC = 512
  const int c = bc & (NC - 1);
  const int t = threadIdx.x;
  const float* row = imp + b * NC;
  const float mine = row[c];
  int cnt = 0;
#pragma unroll
  for (int jj = 0; jj < 2; ++jj) {
    const int j = jj * 256 + t;
    const float o = row[j];
    cnt += (o > mine) || (o == mine && j < c);
  }
  for (int off = 32; off; off >>= 1) cnt += __shfl_down(cnt, off);
  __shared__ int rs[4];
  if ((t & 63) == 0) rs[t >> 6] = cnt;
  __syncthreads();
  const int rank = rs[0] + rs[1] + rs[2] + rs[3];   // block-uniform
  if (rank < NKEEP) return;
  f32x4* op = reinterpret_cast<f32x4*>(out + (size_t)bc * NL);
  const f32x4 z = (f32x4){0.f, 0.f, 0.f, 0.f};
#pragma unroll
  for (int i = 0; i < 8; ++i) __builtin_nontemporal_store(z, op + i * 256 + t);
}

extern "C" void kernel_launch(void* const* d_in, const int* in_sizes, int n_in,
                              void* d_out, int out_size, void* d_ws, size_t ws_size,
                              hipStream_t stream) {
  const float* x   = (const float*)d_in[0];
  const float* c   = (const float*)d_in[1];
  const float* gw1 = (const float*)d_in[2];
  const float* gb1 = (const float*)d_in[3];
  const float* gw2 = (const float*)d_in[4];
  const float* gb2 = (const float*)d_in[5];
  const float* mw1 = (const float*)d_in[6];
  const float* mb1 = (const float*)d_in[7];
  const float* mw2 = (const float*)d_in[8];
  const float* mb2 = (const float*)d_in[9];
  float* out = (float*)d_out;
  char* ws = (char*)d_ws;

  unsigned short* gw1b = (unsigned short*)(ws);             // 131072 B
  unsigned short* gw2b = (unsigned short*)(ws + 131072);    // 131072 B
  float* xsum   = (float*)(ws + 262144);
  float* xsumsq = (float*)(ws + 278528);
  float* csum   = (float*)(ws + 294912);
  float* gsum   = (float*)(ws + 311296);
  float* a_arr  = (float*)(ws + 327680);
  float* d_arr  = (float*)(ws + 344064);
  float* imp    = (float*)(ws + 360448);

  k1_xstats<<<NB * NC, 256, 0, stream>>>(x, xsum, xsumsq, gw1, gw2, gw1b, gw2b, csum, gsum);
  k2_gate<<<NB * (NL / 128), 256, 0, stream>>>(c, gw1b, gw2b, gb1, gb2, gsum, csum);
  k3_final<<<NB, 256, 0, stream>>>(xsum, xsumsq, csum, gsum, mw1, mb1, mw2, mb2, a_arr, d_arr);
  k4_y<<<NB * NC, 256, 0, stream>>>(x, a_arr, d_arr, out, imp);
  k5_apply<<<NB * NC, 256, 0, stream>>>(imp, out);
}

// Round 8
// 164.896 us; speedup vs baseline: 1.9301x; 1.0362x over previous
//
#include <hip/hip_runtime.h>
#include <hip/hip_bf16.h>
#include <math.h>

// Problem constants (B,C,L,H fixed by setup_inputs)
#define NB 8
#define NC 512
#define NL 8192
#define NH 128
#define FEPS 1e-5f
#define NKEEP 358   // int(512*0.7)

typedef __attribute__((ext_vector_type(8))) short short8;
typedef __attribute__((ext_vector_type(4))) float f32x4;

__device__ __forceinline__ unsigned short f2bf(float x) {
  unsigned u = __float_as_uint(x);
  return (unsigned short)((u + 0x7fffu + ((u >> 16) & 1u)) >> 16);  // RNE
}
__device__ __forceinline__ unsigned pack2(float a, float b) {
  return (unsigned)f2bf(a) | ((unsigned)f2bf(b) << 16);
}

// ---------------- K0: convert gate weights to bf16, zero accumulators ----------------
// Separate launch so the merged k12 never depends on intra-launch block ordering (G16).
__global__ __launch_bounds__(256) void k0_prep(
    const float* __restrict__ gw1, const float* __restrict__ gw2,
    unsigned short* __restrict__ gw1b, unsigned short* __restrict__ gw2b,
    float* __restrict__ csum, float* __restrict__ gsum) {
  int i = blockIdx.x * 256 + threadIdx.x;   // 256*256 = 65536 = H*C = C*H
  gw1b[i] = f2bf(gw1[i]);
  gw2b[i] = f2bf(gw2[i]);
  if (i < NB * NC) { csum[i] = 0.f; gsum[i] = 0.f; }
}

// ---------------- K12: gate network (blocks 0..511) + x-stats streamer (blocks 512..4607) ----------------
// R7 post-mortem: k2 is stall-bound at 1.76 TB/s of a 6.3 TB/s pipe (2 lockstep blocks/CU);
// k1 is a pure 5.4 TB/s streamer. Running them as INDEPENDENT BLOCK FAMILIES in one launch
// lets x-waves fill gate-block stall cycles: 2 gate blocks/CU (LDS-capped, 8 waves) + x-blocks
// in the remaining VGPR-allowed wave slots. Gate path = R7's measured-best k2_gate, verbatim.
// x path = R1's measured-best k1 stream, verbatim (weight prep moved to k0).
__global__ __launch_bounds__(256, 2) void k12_gate_x(
    const float* __restrict__ cin, const float* __restrict__ x,
    const unsigned short* __restrict__ gw1b, const unsigned short* __restrict__ gw2b,
    const float* __restrict__ gb1, const float* __restrict__ gb2,
    float* __restrict__ gsum_g, float* __restrict__ csum_g,
    float* __restrict__ xsum, float* __restrict__ xsumsq) {
  // ================= x-stats path (blocks 512..4607): near-roofline streamer =================
  if (blockIdx.x >= 512) {
    const int bc = blockIdx.x - 512;          // 0..NB*NC-1
    const int t = threadIdx.x;
    const float4* xp = reinterpret_cast<const float4*>(x + (size_t)bc * NL);
    float s1 = 0.f, s2 = 0.f;
#pragma unroll
    for (int i = 0; i < 8; ++i) {
      float4 v = xp[i * 256 + t];
      s1 += v.x + v.y + v.z + v.w;
      s2 += v.x * v.x + v.y * v.y + v.z * v.z + v.w * v.w;
    }
    for (int off = 32; off; off >>= 1) { s1 += __shfl_down(s1, off); s2 += __shfl_down(s2, off); }
    __shared__ float r1x[4], r2x[4];
    if ((t & 63) == 0) { r1x[t >> 6] = s1; r2x[t >> 6] = s2; }
    __syncthreads();
    if (t == 0) {
      xsum[bc]   = r1x[0] + r1x[1] + r1x[2] + r1x[3];
      xsumsq[bc] = r2x[0] + r2x[1] + r2x[2] + r2x[3];
    }
    return;
  }

  // ================= gate path (blocks 0..511): R7 k2_gate verbatim =================
  __shared__ __align__(16) unsigned AsU[2 * 128 * 36];     // 36864B: GEMM1 A dbuf; GEMM2 reuses as B dbuf (2x16KB)
  __shared__ __align__(16) unsigned short Hts[4][32][136]; // per-wave H^T [l-local][h], pitch 136
  __shared__ float gsum_s[NC], csum_s[NC], gb2_s[NC];
  __shared__ float gb1_s[NH];

  const int t = threadIdx.x;
  const int lane = t & 63;
  const int w = t >> 6;
  const int r = lane & 15;
  const int kg = lane >> 4;
  const int b = blockIdx.x >> 6;
  const int l0 = (blockIdx.x & 63) * 128;

  // staging roles (A): p = chpair 0..31, q = quad-in-pass
  const int p = t >> 3;
  const int q = t & 7;

  f32x4 acc0[8], acc1[8];
#pragma unroll
  for (int i = 0; i < 8; ++i) { acc0[i] = (f32x4){0.f,0.f,0.f,0.f}; acc1[i] = (f32x4){0.f,0.f,0.f,0.f}; }

  const float* cbase = cin + (size_t)b * NC * NL + l0;
  const unsigned short* gw1r = gw1b + (size_t)r * NC + kg * 8;   // + ht*16*NC + k*64 + kk*32

  // two named staging register sets: A holds even chunks, B holds odd chunks (rule-#20 static)
  f32x4 vaA[4], vbA[4], vaB[4], vbB[4];

#define LOADA(dA, dB, kch) { \
    _Pragma("unroll") \
    for (int pass = 0; pass < 4; ++pass) { \
      const float* cp0 = cbase + (size_t)((kch) * 64 + 2 * p) * NL + 32 * pass + 4 * q; \
      dA[pass] = __builtin_nontemporal_load(reinterpret_cast<const f32x4*>(cp0)); \
      dB[pass] = __builtin_nontemporal_load(reinterpret_cast<const f32x4*>(cp0 + NL)); \
    } }

#define WRITEA(sA, sB, kch, bufi) { \
    unsigned* dst = AsU + (bufi) * (128 * 36); \
    float sa = 0.f, sb = 0.f; \
    _Pragma("unroll") \
    for (int pass = 0; pass < 4; ++pass) { \
      const int ll = 32 * pass + 4 * q; \
      sa += sA[pass].x + sA[pass].y + sA[pass].z + sA[pass].w; \
      sb += sB[pass].x + sB[pass].y + sB[pass].z + sB[pass].w; \
      dst[(ll + 0) * 36 + p] = pack2(sA[pass].x, sB[pass].x); \
      dst[(ll + 1) * 36 + p] = pack2(sA[pass].y, sB[pass].y); \
      dst[(ll + 2) * 36 + p] = pack2(sA[pass].z, sB[pass].z); \
      dst[(ll + 3) * 36 + p] = pack2(sA[pass].w, sB[pass].w); \
    } \
    sa += __shfl_xor(sa, 1); sa += __shfl_xor(sa, 2); sa += __shfl_xor(sa, 4); \
    sb += __shfl_xor(sb, 1); sb += __shfl_xor(sb, 2); sb += __shfl_xor(sb, 4); \
    if ((lane & 7) == 0) { \
      atomicAdd(&csum_s[(kch) * 64 + 2 * p],     sa); \
      atomicAdd(&csum_s[(kch) * 64 + 2 * p + 1], sb); \
    } }

  // prologue: chunks 0 and 1 in flight, init smem, full drain ONCE, stage chunk 0
  LOADA(vaA, vbA, 0)
  LOADA(vaB, vbB, 1)
  for (int i = t; i < NC; i += 256) { gsum_s[i] = 0.f; csum_s[i] = 0.f; gb2_s[i] = gb2[i]; }
  if (t < NH) gb1_s[t] = gb1[t];
  __syncthreads();                      // one-time vmcnt drain, outside the hot loop
  WRITEA(vaA, vbA, 0, 0)
  asm volatile("s_waitcnt lgkmcnt(0)" ::: "memory");
  __builtin_amdgcn_s_barrier();
  __builtin_amdgcn_sched_barrier(0);

  // ---------------- GEMM1 main loop: raw barrier, prefetch never drained ----------------
  for (int k = 0; k < 8; ++k) {
    const unsigned* Abuf = AsU + (k & 1) * (128 * 36);
    // 1) all B-frags for this chunk (L2), BEFORE the deep prefetch -> MFMA waits stop here
    short8 bfr[16];
#pragma unroll
    for (int ht = 0; ht < 8; ++ht) {
      bfr[2 * ht]     = *reinterpret_cast<const short8*>(gw1r + (size_t)(ht * 16) * NC + k * 64);
      bfr[2 * ht + 1] = *reinterpret_cast<const short8*>(gw1r + (size_t)(ht * 16) * NC + k * 64 + 32);
    }
    // 2) A-frags from LDS (written iter k-1, visible via barrier)
    short8 a0[2], a1[2];
#pragma unroll
    for (int kk = 0; kk < 2; ++kk) {
      a0[kk] = *reinterpret_cast<const short8*>(&Abuf[(32 * w + r)      * 36 + 16 * kk + 4 * kg]);
      a1[kk] = *reinterpret_cast<const short8*>(&Abuf[(32 * w + 16 + r) * 36 + 16 * kk + 4 * kg]);
    }
    __builtin_amdgcn_sched_barrier(0);
    // 3) stage chunk k+1 (counted vmcnt on its reg set; loads had a full iteration of flight)
    if (k < 7) {
      if ((k & 1) == 0) { WRITEA(vaB, vbB, k + 1, 1) } else { WRITEA(vaA, vbA, k + 1, 0) }
    }
    __builtin_amdgcn_sched_barrier(0);
    // 4) deep prefetch chunk k+2 into the freed set — youngest VMEM; nothing below waits on it
    if (k < 6) {
      if ((k & 1) == 0) { LOADA(vaA, vbA, k + 2) } else { LOADA(vaB, vbB, k + 2) }
    }
    __builtin_amdgcn_sched_barrier(0);
    // 5) MFMA: waits cover bfr (older than prefetch) and a-frags (lgkm) only
#pragma unroll
    for (int kk = 0; kk < 2; ++kk) {
#pragma unroll
      for (int ht = 0; ht < 8; ++ht) {
        acc0[ht] = __builtin_amdgcn_mfma_f32_16x16x32_bf16(a0[kk], bfr[2 * ht + kk], acc0[ht], 0, 0, 0);
        acc1[ht] = __builtin_amdgcn_mfma_f32_16x16x32_bf16(a1[kk], bfr[2 * ht + kk], acc1[ht], 0, 0, 0);
      }
    }
    // 6) publish my DS ops, raw barrier — NO vmcnt drain
    __builtin_amdgcn_sched_barrier(0);
    asm volatile("s_waitcnt lgkmcnt(0)" ::: "memory");
    __builtin_amdgcn_s_barrier();
    __builtin_amdgcn_sched_barrier(0);
  }

  // epilogue: bias+relu -> Hts (D map: col=lane&15, row=(lane>>4)*4+reg)
#pragma unroll
  for (int ht = 0; ht < 8; ++ht) {
    const float bias = gb1_s[16 * ht + r];
#pragma unroll
    for (int reg = 0; reg < 4; ++reg) {
      Hts[w][4 * kg + reg][16 * ht + r]      = f2bf(fmaxf(acc0[ht][reg] + bias, 0.f));
      Hts[w][16 + 4 * kg + reg][16 * ht + r] = f2bf(fmaxf(acc1[ht][reg] + bias, 0.f));
    }
  }
  // wave-local write->read: per-wave DS ordering, no barrier needed
  short8 af0[4], af1[4];
#pragma unroll
  for (int kk = 0; kk < 4; ++kk) {
    af0[kk] = *reinterpret_cast<const short8*>(&Hts[w][r][32 * kk + 8 * kg]);
    af1[kk] = *reinterpret_cast<const short8*>(&Hts[w][16 + r][32 * kk + 8 * kg]);
  }

  // ---------------- GEMM2: gsum[c] += sigmoid(H^T . gw2[c] + gb2), B dbuf in AsU space ----------------
  unsigned short* Bs2 = reinterpret_cast<unsigned short*>(AsU);
  const int crow = lane >> 4;    // B2: row offset 0..3
  const int bs2  = lane & 15;    // B2: slot 0..15
  short8 bv[4];

#define LOADB2(ccn) { \
    _Pragma("unroll") \
    for (int j = 0; j < 4; ++j) { \
      const int cl = 16 * w + 4 * j + crow; \
      bv[j] = *reinterpret_cast<const short8*>(gw2b + (size_t)((ccn) * 64 + cl) * NH + bs2 * 8); \
    } }
#define WRITEB2(ccn) { \
    unsigned short* dstb = Bs2 + ((ccn) & 1) * 8192; \
    _Pragma("unroll") \
    for (int j = 0; j < 4; ++j) { \
      const int cl = 16 * w + 4 * j + crow; \
      *reinterpret_cast<short8*>(&dstb[cl * 128 + ((bs2 ^ (cl & 7)) * 8)]) = bv[j]; \
    } }

  LOADB2(0)
  WRITEB2(0)                      // safe: all waves past GEMM1's final barrier
  __syncthreads();
  for (int cc = 0; cc < 8; ++cc) {
    if (cc < 7) LOADB2(cc + 1)
    const unsigned short* Bbuf = Bs2 + (cc & 1) * 8192;
#pragma unroll
    for (int ctt = 0; ctt < 4; ++ctt) {
      f32x4 z0 = (f32x4){0.f,0.f,0.f,0.f}, z1 = (f32x4){0.f,0.f,0.f,0.f};
#pragma unroll
      for (int kk = 0; kk < 4; ++kk) {
        const short8 bf = *reinterpret_cast<const short8*>(
            &Bbuf[(16 * ctt + r) * 128 + (((4 * kk + kg) ^ (r & 7)) * 8)]);
        z0 = __builtin_amdgcn_mfma_f32_16x16x32_bf16(af0[kk], bf, z0, 0, 0, 0);
        z1 = __builtin_amdgcn_mfma_f32_16x16x32_bf16(af1[kk], bf, z1, 0, 0, 0);
      }
      const float bias = gb2_s[cc * 64 + 16 * ctt + r];
      float s = 0.f;
#pragma unroll
      for (int reg = 0; reg < 4; ++reg) {
        s += 1.f / (1.f + __expf(-(z0[reg] + bias)));
        s += 1.f / (1.f + __expf(-(z1[reg] + bias)));
      }
      s += __shfl_xor(s, 16);
      s += __shfl_xor(s, 32);
      if (lane < 16) atomicAdd(&gsum_s[cc * 64 + 16 * ctt + lane], s);
    }
    if (cc < 7) WRITEB2(cc + 1)
    __syncthreads();
  }
  for (int i = t; i < NC; i += 256) {
    atomicAdd(&gsum_g[b * NC + i], gsum_s[i]);
    atomicAdd(&csum_g[b * NC + i], csum_s[i]);
  }
}

// ---------------- K3: finalize stats + affine MLP -> per-(b,c) y = A*x + D ----------------
__global__ __launch_bounds__(256) void k3_final(
    const float* __restrict__ xsum, const float* __restrict__ xsumsq,
    const float* __restrict__ csum, const float* __restrict__ gsum,
    const float* __restrict__ mw1, const float* __restrict__ mb1,
    const float* __restrict__ mw2, const float* __restrict__ mb2,
    float* __restrict__ a_arr, float* __restrict__ d_arr) {
  __shared__ __align__(16) float cp[NC];
  __shared__ __align__(16) float hm[NH];
  __shared__ float gbv[2 * NC];
  __shared__ double red[8];
  __shared__ float mu_l_s, sig_l_s;
  const int b = blockIdx.x, t = threadIdx.x;

  double s1 = 0.0, s2 = 0.0;
  for (int c = t; c < NC; c += 256) { s1 += (double)xsum[b * NC + c]; s2 += (double)xsumsq[b * NC + c]; }
  for (int off = 32; off; off >>= 1) { s1 += __shfl_down(s1, off); s2 += __shfl_down(s2, off); }
  if ((t & 63) == 0) { red[(t >> 6) * 2] = s1; red[(t >> 6) * 2 + 1] = s2; }
  for (int c = t; c < NC; c += 256) cp[c] = csum[b * NC + c] * (1.f / NL);
  __syncthreads();
  if (t == 0) {
    double S1 = red[0] + red[2] + red[4] + red[6];
    double S2 = red[1] + red[3] + red[5] + red[7];
    double n = (double)NC * NL;
    double mu = S1 / n;
    double var = S2 / n - mu * mu;
    mu_l_s = (float)mu;
    sig_l_s = (float)sqrt(var + (double)FEPS);
  }
  __syncthreads();
  if (t < NH) {
    const float4* row = reinterpret_cast<const float4*>(mw1 + (size_t)t * NC);
    const float4* cpv = reinterpret_cast<const float4*>(cp);
    float acc = mb1[t];
    for (int i = 0; i < NC / 4; ++i) {
      float4 wv = row[i], xv = cpv[i];
      acc += wv.x * xv.x + wv.y * xv.y + wv.z * xv.z + wv.w * xv.w;
    }
    hm[t] = fmaxf(acc, 0.f);
  }
  __syncthreads();
  for (int o = t; o < 2 * NC; o += 256) {
    const float4* row = reinterpret_cast<const float4*>(mw2 + (size_t)o * NH);
    const float4* hv = reinterpret_cast<const float4*>(hm);
    float acc = mb2[o];
    for (int i = 0; i < NH / 4; ++i) {
      float4 wv = row[i], xv = hv[i];
      acc += wv.x * xv.x + wv.y * xv.y + wv.z * xv.z + wv.w * xv.w;
    }
    gbv[o] = acc;
  }
  __syncthreads();
  const float mu_l = mu_l_s, sig_l = sig_l_s;
  for (int c = t; c < NC; c += 256) {
    float gm = gsum[b * NC + c] * (1.f / NL);
    double mu_c = (double)xsum[b * NC + c] / NL;
    double var_c = (double)xsumsq[b * NC + c] / NL - mu_c * mu_c;
    float sig_c = (float)sqrt(var_c + (double)FEPS);
    float mu = gm * (float)mu_c + (1.f - gm) * mu_l;
    float sg = gm * sig_c + (1.f - gm) * sig_l;
    float gamma = gbv[c], beta = gbv[NC + c];
    float A = (1.f + gamma) / sg;
    a_arr[b * NC + c] = A;
    d_arr[b * NC + c] = beta - A * mu;
  }
}

// ---------------- K4: y = A*x + D, nt stores, imp = sum |y| ----------------
__global__ __launch_bounds__(256) void k4_y(
    const float* __restrict__ x, const float* __restrict__ a_arr,
    const float* __restrict__ d_arr, float* __restrict__ out, float* __restrict__ imp) {
  const int bc = blockIdx.x, t = threadIdx.x;
  const float A = a_arr[bc], D = d_arr[bc];
  const f32x4* xp = reinterpret_cast<const f32x4*>(x + (size_t)bc * NL);
  f32x4* op = reinterpret_cast<f32x4*>(out + (size_t)bc * NL);
  float s = 0.f;
#pragma unroll
  for (int i = 0; i < 8; ++i) {
    f32x4 v = __builtin_nontemporal_load(xp + i * 256 + t);   // last use of x
    f32x4 y;
    y.x = fmaf(A, v.x, D); y.y = fmaf(A, v.y, D);
    y.z = fmaf(A, v.z, D); y.w = fmaf(A, v.w, D);
    s += fabsf(y.x) + fabsf(y.y) + fabsf(y.z) + fabsf(y.w);
    __builtin_nontemporal_store(y, op + i * 256 + t);         // out never re-read
  }
  for (int off = 32; off; off >>= 1) s += __shfl_down(s, off);
  __shared__ float rs[4];
  if ((t & 63) == 0) rs[t >> 6] = s;
  __syncthreads();
  if (t == 0) imp[bc] = rs[0] + rs[1] + rs[2] + rs[3];
}

// ---------------- K5: fused top-k rank (jax.lax.top_k tie semantics) + zero dropped rows ----------------
__global__ __launch_bounds__(256) void k5_apply(
    const float* __restrict__ imp, float* __restrict__ out) {
  const int bc = blockIdx.x;
  const int b = bc >> 9;            // NC = 512
  const int c = bc & (NC - 1);
  const int t = threadIdx.x;
  const float* row = imp + b * NC;
  const float mine = row[c];
  int cnt = 0;
#pragma unroll
  for (int jj = 0; jj < 2; ++jj) {
    const int j = jj * 256 + t;
    const float o = row[j];
    cnt += (o > mine) || (o == mine && j < c);
  }
  for (int off = 32; off; off >>= 1) cnt += __shfl_down(cnt, off);
  __shared__ int rs[4];
  if ((t & 63) == 0) rs[t >> 6] = cnt;
  __syncthreads();
  const int rank = rs[0] + rs[1] + rs[2] + rs[3];   // block-uniform
  if (rank < NKEEP) return;
  f32x4* op = reinterpret_cast<f32x4*>(out + (size_t)bc * NL);
  const f32x4 z = (f32x4){0.f, 0.f, 0.f, 0.f};
#pragma unroll
  for (int i = 0; i < 8; ++i) __builtin_nontemporal_store(z, op + i * 256 + t);
}

extern "C" void kernel_launch(void* const* d_in, const int* in_sizes, int n_in,
                              void* d_out, int out_size, void* d_ws, size_t ws_size,
                              hipStream_t stream) {
  const float* x   = (const float*)d_in[0];
  const float* c   = (const float*)d_in[1];
  const float* gw1 = (const float*)d_in[2];
  const float* gb1 = (const float*)d_in[3];
  const float* gw2 = (const float*)d_in[4];
  const float* gb2 = (const float*)d_in[5];
  const float* mw1 = (const float*)d_in[6];
  const float* mb1 = (const float*)d_in[7];
  const float* mw2 = (const float*)d_in[8];
  const float* mb2 = (const float*)d_in[9];
  float* out = (float*)d_out;
  char* ws = (char*)d_ws;

  unsigned short* gw1b = (unsigned short*)(ws);             // 131072 B
  unsigned short* gw2b = (unsigned short*)(ws + 131072);    // 131072 B
  float* xsum   = (float*)(ws + 262144);
  float* xsumsq = (float*)(ws + 278528);
  float* csum   = (float*)(ws + 294912);
  float* gsum   = (float*)(ws + 311296);
  float* a_arr  = (float*)(ws + 327680);
  float* d_arr  = (float*)(ws + 344064);
  float* imp    = (float*)(ws + 360448);

  k0_prep<<<256, 256, 0, stream>>>(gw1, gw2, gw1b, gw2b, csum, gsum);
  k12_gate_x<<<512 + NB * NC, 256, 0, stream>>>(c, x, gw1b, gw2b, gb1, gb2,
                                                gsum, csum, xsum, xsumsq);
  k3_final<<<NB, 256, 0, stream>>>(xsum, xsumsq, csum, gsum, mw1, mb1, mw2, mb2, a_arr, d_arr);
  k4_y<<<NB * NC, 256, 0, stream>>>(x, a_arr, d_arr, out, imp);
  k5_apply<<<NB * NC, 256, 0, stream>>>(imp, out);
}